// Round 11
// baseline (48.392 us; speedup 1.0000x reference)
//
#include <hip/hip_runtime.h>
#include <math.h>

// QConv2d: x (32,4,64,64) f32, params (4,8,16,16) f32 -> out (32,32,32,32) f32
// B=32 C=4 H=W=64, KH=KW=2 stride 2 -> px=py=32, NW=4, DIM=16, D=8, M=32768

#define TAYLOR_N 9

// ---------------- Kernel 1: zero the output (all 1024 blocks) + expm (blocks<32)
// W'[c*8+d][j][i] = expm(SH)[i][j] * (-i)^popc(i)
__global__ __launch_bounds__(256) void prep_kernel(const float* __restrict__ params,
                                                   float2* __restrict__ wp,
                                                   float4* __restrict__ outz) {
    outz[blockIdx.x * 256 + threadIdx.x] = make_float4(0.f, 0.f, 0.f, 0.f);
    if (blockIdx.x >= 32) return;

    __shared__ float2 X[256];
    __shared__ float2 P0[256];
    __shared__ float2 P1[256];
    __shared__ float red[256];
    __shared__ float srow[16];
    __shared__ int ssexp;

    const int bid = blockIdx.x;      // c*8 + d
    const int tid = threadIdx.x;
    const int i = tid >> 4, j = tid & 15;

    const float* pm = params + bid * 256;
    float pij = pm[i * 16 + j];
    float pji = pm[j * 16 + i];
    float ar = pij - pji;   // asym -> real part of SH
    float ai = pij + pji;   // sym  -> imag part of SH
    red[tid] = fabsf(ar) + fabsf(ai);
    __syncthreads();
    if (j == 0) {
        float s = 0.f;
        for (int t = 0; t < 16; ++t) s += red[i * 16 + t];
        srow[i] = s;
    }
    __syncthreads();
    if (tid == 0) {
        float mx = 0.f;
        for (int t = 0; t < 16; ++t) mx = fmaxf(mx, srow[t]);
        int se = 0;
        while (mx > 0.5f && se < 40) { mx *= 0.5f; se++; }
        ssexp = se;
    }
    __syncthreads();
    const int sexp = ssexp;
    const float scale = exp2f((float)(-sexp));
    const float xr = ar * scale, xi = ai * scale;
    X[tid] = make_float2(xr, xi);
    float2 p = make_float2(xr / TAYLOR_N + ((i == j) ? 1.f : 0.f), xi / TAYLOR_N);
    P0[tid] = p;
    __syncthreads();

    float2 Xr[16];
    #pragma unroll
    for (int t = 0; t < 16; ++t) Xr[t] = X[i * 16 + t];

    float2* cur = P0;
    float2* nxt = P1;
    for (int k = TAYLOR_N - 1; k >= 1; --k) {
        float accr = 0.f, acci = 0.f;
        #pragma unroll
        for (int t = 0; t < 16; ++t) {
            float2 a = Xr[t];
            float2 bb = cur[t * 16 + j];
            accr += a.x * bb.x - a.y * bb.y;
            acci += a.x * bb.y + a.y * bb.x;
        }
        float inv = 1.f / (float)k;
        float2 np = make_float2(accr * inv + ((i == j) ? 1.f : 0.f), acci * inv);
        __syncthreads();
        nxt[tid] = np;
        __syncthreads();
        float2* tmp = cur; cur = nxt; nxt = tmp;
    }
    for (int sq = 0; sq < sexp; ++sq) {
        float accr = 0.f, acci = 0.f;
        #pragma unroll
        for (int t = 0; t < 16; ++t) {
            float2 a = cur[i * 16 + t];
            float2 bb = cur[t * 16 + j];
            accr += a.x * bb.x - a.y * bb.y;
            acci += a.x * bb.y + a.y * bb.x;
        }
        __syncthreads();
        nxt[tid] = make_float2(accr, acci);
        __syncthreads();
        float2* tmp = cur; cur = nxt; nxt = tmp;
    }
    float2 e = cur[tid];
    int pc = __popc(i) & 3;
    float2 o;
    if (pc == 0)      o = make_float2( e.x,  e.y);
    else if (pc == 1) o = make_float2( e.y, -e.x);
    else if (pc == 2) o = make_float2(-e.x, -e.y);
    else              o = make_float2(-e.y,  e.x);
    wp[(bid * 16 + j) * 16 + i] = o;
}

// Fast acos: A&S 4.4.45, |abs err| <= 6.8e-5 over [-1,1]
__device__ __forceinline__ float acos_fast(float t) {
    float ax = fabsf(t);
    float p = fmaf(ax, -0.0187293f, 0.0742610f);
    p = fmaf(ax, p, -0.2121144f);
    p = fmaf(ax, p, 1.5707288f);
    float f = sqrtf(1.0f - ax) * p;
    return (t >= 0.f) ? f : (3.14159265358979f - f);
}

// build r[16] for one site from 4 angles (wire0 = MSB of k)
#define BUILD_R(rr, T0, T1, T2, T3) do {                                   \
    float sn0, cs0, sn1, cs1, sn2, cs2, sn3, cs3;                          \
    __sincosf((T0) * 0.5f, &sn0, &cs0);                                    \
    __sincosf((T1) * 0.5f, &sn1, &cs1);                                    \
    __sincosf((T2) * 0.5f, &sn2, &cs2);                                    \
    __sincosf((T3) * 0.5f, &sn3, &cs3);                                    \
    float p00 = cs0 * cs1, p01 = cs0 * sn1, p10 = sn0 * cs1, p11 = sn0 * sn1; \
    float e0 = p00 * cs2, e1 = p00 * sn2, e2 = p01 * cs2, e3 = p01 * sn2;  \
    float e4 = p10 * cs2, e5 = p10 * sn2, e6 = p11 * cs2, e7 = p11 * sn2;  \
    rr[0]  = e0 * cs3; rr[1]  = e0 * sn3; rr[2]  = e1 * cs3; rr[3]  = e1 * sn3; \
    rr[4]  = e2 * cs3; rr[5]  = e2 * sn3; rr[6]  = e3 * cs3; rr[7]  = e3 * sn3; \
    rr[8]  = e4 * cs3; rr[9]  = e4 * sn3; rr[10] = e5 * cs3; rr[11] = e5 * sn3; \
    rr[12] = e6 * cs3; rr[13] = e6 * sn3; rr[14] = e7 * cs3; rr[15] = e7 * sn3; \
} while (0)

// DPP cross-lane (VALU pipe, not DS): quad_perm xor1=0xB1, xor2=0x4E;
// row_ror4=0x124, row_ror8=0x128 (16-lane row). Plain-sum uses of ror are
// direction-agnostic (orbit {i,i+4,i+8,i+12} is closed).
#define DPP_F(v, ctrl) __int_as_float(__builtin_amdgcn_update_dpp( \
    0, __float_as_int(v), (ctrl), 0xF, 0xF, false))

// ---------------- Kernel 2: main compute ------------------------------------
// Wave layout: lane = msub(2b) | cidx(2b) | jg(2b). Each lane PERMANENTLY
// holds W' rows {jg*4..jg*4+3} of channel cidx in VGPRs (128 regs, loaded
// once) -> zero per-use W delivery cost (R1-R10 all bottlenecked on W
// delivery: s_load latency / per-lane VMEM / DS-pipe serialization).
// Per site: 4x32 complex FMA per lane; quad DPP butterfly (signed via
// per-lane +-1 fmaf) leaves t_w (w=[2,1,0,3]) on lane jg; acos per lane;
// c-sum via DPP row_ror4+ror8 (fixed order -> deterministic); lane cidx==0
// stores. No atomics, no LDS, output written exactly once.
// grid = 8(d) * 64(nb) blocks x 256 thr = 2048 waves = 2/SIMD.
__global__ __launch_bounds__(256)
__attribute__((amdgpu_waves_per_eu(2, 4)))
void qconv_kernel(const float* __restrict__ x,
                  const float2* __restrict__ wp,
                  float* __restrict__ out) {
    const int bidx = blockIdx.x;      // d*64 + nb
    const int d  = bidx >> 6;
    const int nb = bidx & 63;
    const int tid  = threadIdx.x;
    const int wave = tid >> 6;
    const int lane = tid & 63;
    const int jg   = lane & 3;
    const int cidx = (lane >> 2) & 3;
    const int msub = lane >> 4;       // 0..3
    const int waveid = nb * 4 + wave; // 0..255 per d

    // Walsh lane constants: stage signs and output-wire mapping
    const float s1 = (jg & 1) ? -1.f : 1.f;
    const float s2 = (jg & 2) ? -1.f : 1.f;
    const int wsel = (jg == 0) ? 2 : (jg == 1) ? 1 : (jg == 2) ? 0 : 3;
    const int och  = (d << 2) + wsel;

    // persistent W': rows j = jg*4+jl of channel cidx (once per kernel)
    float Wr[4][16], Wi[4][16];
    {
        const float4* wb4 = (const float4*)(wp + (((cidx << 3) + d) << 8) + (jg << 6));
        #pragma unroll
        for (int u = 0; u < 32; ++u) {
            float4 v = wb4[u];
            const int jl = u >> 3, k0 = (u & 7) * 2;
            Wr[jl][k0] = v.x; Wi[jl][k0] = v.y;
            Wr[jl][k0 + 1] = v.z; Wi[jl][k0 + 1] = v.w;
        }
    }

    const int m0 = waveid * 128 + msub;   // 32 steps x 4 sites
    float2 xa, xb;
    {
        const int m = m0;
        const int b = m >> 10, ix = (m >> 5) & 31, iy = m & 31;
        const float* xq = x + ((((b << 2) + cidx) << 6) + 2 * ix) * 64 + 2 * iy;
        xa = *(const float2*)xq;
        xb = *(const float2*)(xq + 64);
    }

    #pragma unroll 1
    for (int t = 0; t < 32; ++t) {
        const float2 cxa = xa, cxb = xb;
        const int m = m0 + t * 4;
        if (t < 31) {                       // prefetch next site's angles
            const int mn = m + 4;
            const int b = mn >> 10, ix = (mn >> 5) & 31, iy = mn & 31;
            const float* xq = x + ((((b << 2) + cidx) << 6) + 2 * ix) * 64 + 2 * iy;
            xa = *(const float2*)xq;
            xb = *(const float2*)(xq + 64);
        }

        float r[16];
        BUILD_R(r, cxa.x, cxa.y, cxb.x, cxb.y);

        float yr0 = 0.f, yi0 = 0.f, yr1 = 0.f, yi1 = 0.f;
        float yr2 = 0.f, yi2 = 0.f, yr3 = 0.f, yi3 = 0.f;
        #pragma unroll
        for (int k = 0; k < 16; ++k) {
            yr0 = fmaf(Wr[0][k], r[k], yr0); yi0 = fmaf(Wi[0][k], r[k], yi0);
            yr1 = fmaf(Wr[1][k], r[k], yr1); yi1 = fmaf(Wi[1][k], r[k], yi1);
            yr2 = fmaf(Wr[2][k], r[k], yr2); yi2 = fmaf(Wi[2][k], r[k], yi2);
            yr3 = fmaf(Wr[3][k], r[k], yr3); yi3 = fmaf(Wi[3][k], r[k], yi3);
        }
        float q0 = fmaf(yr0, yr0, yi0 * yi0);
        float q1 = fmaf(yr1, yr1, yi1 * yi1);
        float q2 = fmaf(yr2, yr2, yi2 * yi2);
        float q3 = fmaf(yr3, yr3, yi3 * yi3);

        // lane partials: S (plain sum), A2/A3 (within-lane signed by jl bits)
        float pa = q0 + q1, pb = q2 + q3, pc = q0 - q1, pd = q2 - q3;
        float S = pa + pb, A2 = pa - pb, A3 = pc + pd;

        // quad butterfly: T on lane jg=2 -> t0 (j bit3), jg=1 -> t1 (j bit2)
        float T = fmaf(s1, S, DPP_F(S, 0xB1));
        T = fmaf(s2, T, DPP_F(T, 0x4E));
        float U2 = A2 + DPP_F(A2, 0xB1); U2 = U2 + DPP_F(U2, 0x4E);  // t2
        float U3 = A3 + DPP_F(A3, 0xB1); U3 = U3 + DPP_F(U3, 0x4E);  // t3

        float val = (jg == 0) ? U2 : (jg == 3) ? U3 : T;
        val = fminf(fmaxf(val, -1.f), 1.f);
        float ac = acos_fast(val);

        // sum over the 4 channels (lane bits 2-3): fixed-order, deterministic
        float cs = ac + DPP_F(ac, 0x124);
        cs = cs + DPP_F(cs, 0x128);

        if (cidx == 0) {
            const int b = m >> 10, ix = (m >> 5) & 31, iy = m & 31;
            out[(((b << 5) + och) << 10) + (ix << 5) + iy] = cs;
        }
    }
}

extern "C" void kernel_launch(void* const* d_in, const int* in_sizes, int n_in,
                              void* d_out, int out_size, void* d_ws, size_t ws_size,
                              hipStream_t stream) {
    const float* x = (const float*)d_in[0];
    const float* params = (const float*)d_in[1];
    float* out = (float*)d_out;
    float2* wp = (float2*)d_ws;   // 32 * 256 * 8 bytes = 64 KiB

    prep_kernel<<<1024, 256, 0, stream>>>(params, wp, (float4*)out);
    qconv_kernel<<<8 * 64, 256, 0, stream>>>(x, wp, out);
}

// Round 12
// 26.213 us; speedup vs baseline: 1.8461x; 1.8461x over previous
//
#include <hip/hip_runtime.h>
#include <math.h>

// QConv2d: x (32,4,64,64) f32, params (4,8,16,16) f32 -> out (32,32,32,32) f32
// B=32 C=4 H=W=64, KH=KW=2 stride 2 -> px=py=32, NW=4, DIM=16, D=8, M=32768

#define TAYLOR_N 9

typedef __attribute__((ext_vector_type(8))) short bf16x8;   // 8 bf16 (4 VGPR)
typedef __attribute__((ext_vector_type(4))) float f32x4;    // MFMA C/D

// RNE float->bf16 (returns low 16 bits)
__device__ __forceinline__ unsigned bfr(float x) {
    unsigned u = __float_as_uint(x);
    return (u + 0x7FFFu + ((u >> 16) & 1u)) >> 16;
}
__device__ __forceinline__ float bfhi(float x) {   // bf16-rounded value as f32
    return __uint_as_float(bfr(x) << 16);
}

// ---------------- Kernel 1: expm + A-fragment build (32 blocks) --------------
// W'[j][k] = expm(SH)[k][j] * (-i)^popc(k).  A-frag (16x16x32 bf16 layout:
// row=lane&15, kk=(lane>>4)*8+e): kk<16 -> bf16_hi(W'[j][kk]), kk>=16 ->
// bf16(lo) of W'[j][kk-16].  wfrag[cd][lane][8 uints]: words 0-3 = Wr, 4-7 = Wi.
__global__ __launch_bounds__(256) void prep_kernel(const float* __restrict__ params,
                                                   unsigned* __restrict__ wfrag) {
    __shared__ float2 X[256];
    __shared__ float2 P0[256];
    __shared__ float2 P1[256];
    __shared__ float red[256];
    __shared__ float srow[16];
    __shared__ int ssexp;

    const int bid = blockIdx.x;      // c*8 + d
    const int tid = threadIdx.x;
    const int i = tid >> 4, j = tid & 15;

    const float* pm = params + bid * 256;
    float pij = pm[i * 16 + j];
    float pji = pm[j * 16 + i];
    float ar = pij - pji;   // asym -> real part of SH
    float ai = pij + pji;   // sym  -> imag part of SH
    red[tid] = fabsf(ar) + fabsf(ai);
    __syncthreads();
    if (j == 0) {
        float s = 0.f;
        for (int t = 0; t < 16; ++t) s += red[i * 16 + t];
        srow[i] = s;
    }
    __syncthreads();
    if (tid == 0) {
        float mx = 0.f;
        for (int t = 0; t < 16; ++t) mx = fmaxf(mx, srow[t]);
        int se = 0;
        while (mx > 0.5f && se < 40) { mx *= 0.5f; se++; }
        ssexp = se;
    }
    __syncthreads();
    const int sexp = ssexp;
    const float scale = exp2f((float)(-sexp));
    const float xr = ar * scale, xi = ai * scale;
    X[tid] = make_float2(xr, xi);
    float2 p = make_float2(xr / TAYLOR_N + ((i == j) ? 1.f : 0.f), xi / TAYLOR_N);
    P0[tid] = p;
    __syncthreads();

    float2 Xr[16];
    #pragma unroll
    for (int t = 0; t < 16; ++t) Xr[t] = X[i * 16 + t];

    float2* cur = P0;
    float2* nxt = P1;
    for (int k = TAYLOR_N - 1; k >= 1; --k) {
        float accr = 0.f, acci = 0.f;
        #pragma unroll
        for (int t = 0; t < 16; ++t) {
            float2 a = Xr[t];
            float2 bb = cur[t * 16 + j];
            accr += a.x * bb.x - a.y * bb.y;
            acci += a.x * bb.y + a.y * bb.x;
        }
        float inv = 1.f / (float)k;
        float2 np = make_float2(accr * inv + ((i == j) ? 1.f : 0.f), acci * inv);
        __syncthreads();
        nxt[tid] = np;
        __syncthreads();
        float2* tmp = cur; cur = nxt; nxt = tmp;
    }
    for (int sq = 0; sq < sexp; ++sq) {
        float accr = 0.f, acci = 0.f;
        #pragma unroll
        for (int t = 0; t < 16; ++t) {
            float2 a = cur[i * 16 + t];
            float2 bb = cur[t * 16 + j];
            accr += a.x * bb.x - a.y * bb.y;
            acci += a.x * bb.y + a.y * bb.x;
        }
        __syncthreads();
        nxt[tid] = make_float2(accr, acci);
        __syncthreads();
        float2* tmp = cur; cur = nxt; nxt = tmp;
    }
    // E[i][j] = U[i][j]; W'[j][k=i] = U[i][j]*(-i)^popc(i). Stash W' in X[j*16+k].
    float2 e = cur[tid];
    int pc = __popc(i) & 3;
    float2 o;
    if (pc == 0)      o = make_float2( e.x,  e.y);
    else if (pc == 1) o = make_float2( e.y, -e.x);
    else if (pc == 2) o = make_float2(-e.x, -e.y);
    else              o = make_float2(-e.y,  e.x);
    __syncthreads();                    // all reads of X (Xr hoist) long done
    X[(tid & 15) * 16 + (tid >> 4)] = o;
    __syncthreads();

    // A-fragment emit: thread t -> lane = t&63, pair pr = t>>6 (elements 2pr,2pr+1)
    {
        const int lane = tid & 63;
        const int pr = tid >> 6;
        const int jj = lane & 15, hh = lane >> 4;
        const int kbase = (hh & 1) * 8;
        const int e0 = pr * 2;
        float2 s0 = X[jj * 16 + kbase + e0];
        float2 s1 = X[jj * 16 + kbase + e0 + 1];
        unsigned r0, r1, i0, i1;
        if (hh < 2) {                   // hi halves: kk 0..15
            r0 = bfr(s0.x); r1 = bfr(s1.x);
            i0 = bfr(s0.y); i1 = bfr(s1.y);
        } else {                        // lo halves: kk 16..31
            r0 = bfr(s0.x - bfhi(s0.x)); r1 = bfr(s1.x - bfhi(s1.x));
            i0 = bfr(s0.y - bfhi(s0.y)); i1 = bfr(s1.y - bfhi(s1.y));
        }
        unsigned base = (unsigned)(bid * 64 + lane) * 8u;
        wfrag[base + pr]      = r0 | (r1 << 16);
        wfrag[base + 4 + pr]  = i0 | (i1 << 16);
    }
}

// Fast acos: A&S 4.4.45, |abs err| <= 6.8e-5 over [-1,1]
__device__ __forceinline__ float acos_fast(float t) {
    float ax = fabsf(t);
    float p = fmaf(ax, -0.0187293f, 0.0742610f);
    p = fmaf(ax, p, -0.2121144f);
    p = fmaf(ax, p, 1.5707288f);
    float f = sqrtf(1.0f - ax) * p;
    return (t >= 0.f) ? f : (3.14159265358979f - f);
}

// ---------------- Kernel 2: MFMA main compute --------------------------------
// Wave = 16 sites (site = lane&15, hh = lane>>4). Per c: build B-frags once
// (trig reused across all 8 d!). Per (c,d): Y = [Whi|Wlo]x[rhi|rhi] (+)
// [Whi|Wlo]x[rlo|0]  -> full split-bf16 product, fp32 accum. C layout
// (HW-verified): col=lane&15=site, row j = hh*4+reg. Walsh: per-lane partials
// + 3 shfl_xor give t_w for w=hh on every lane; one acos/lane; plain store
// (each output written exactly once -> no atomics, no zeroing).
// grid = 512 blocks x 256 thr = 2048 waves = 2/SIMD.
__global__ __launch_bounds__(256)
__attribute__((amdgpu_waves_per_eu(2, 4)))
void qconv_kernel(const float* __restrict__ x,
                  const unsigned* __restrict__ wfrag,
                  float* __restrict__ out) {
    const int tid = threadIdx.x;
    const int lane = tid & 63;
    const int s = lane & 15;
    const int hh = lane >> 4;
    const int wave = blockIdx.x * 4 + (tid >> 6);
    const int m = wave * 16 + s;
    const int b = m >> 10, ix = (m >> 5) & 31, iy = m & 31;

    const bf16x8* wf = (const bf16x8*)wfrag;

    // ---- B fragments for the 4 channels: bm = [rhi|rhi], bc = [rlo|0] ----
    bf16x8 bm[4], bc[4];
    const float lsc = (hh < 2) ? 1.f : 0.f;   // zero the lo-frag on kk>=16 lanes
    #pragma unroll
    for (int c = 0; c < 4; ++c) {
        const float* xc = x + (((b * 4 + c) * 64 + 2 * ix) * 64 + 2 * iy);
        float2 xa = *(const float2*)xc;         // theta0, theta1 (row 2ix)
        float2 xb = *(const float2*)(xc + 64);  // theta2, theta3 (row 2ix+1)
        float sn0, cs0, sn1, cs1, sn2, cs2, sn3, cs3;
        __sincosf(xa.x * 0.5f, &sn0, &cs0);
        __sincosf(xa.y * 0.5f, &sn1, &cs1);
        __sincosf(xb.x * 0.5f, &sn2, &cs2);
        __sincosf(xb.y * 0.5f, &sn3, &cs3);
        // this lane supplies k = (hh&1)*8 + e (k bit3 = wire0 state)
        float f0 = (hh & 1) ? sn0 : cs0;
        float g0 = f0 * cs1, g1 = f0 * sn1;
        float h0 = g0 * cs2, h1 = g0 * sn2, h2 = g1 * cs2, h3 = g1 * sn2;
        float r[8];
        r[0] = h0 * cs3; r[1] = h0 * sn3; r[2] = h1 * cs3; r[3] = h1 * sn3;
        r[4] = h2 * cs3; r[5] = h2 * sn3; r[6] = h3 * cs3; r[7] = h3 * sn3;
        #pragma unroll
        for (int e = 0; e < 8; ++e) {
            unsigned hb = bfr(r[e]);
            bm[c][e] = (short)hb;
            float lo = (r[e] - __uint_as_float(hb << 16)) * lsc;
            bc[c][e] = (short)bfr(lo);
        }
    }

    const float sgn0 = (hh & 2) ? -1.f : 1.f;   // w=0 sign: j bit3 = hh>>1
    const float sgn1 = (hh & 1) ? -1.f : 1.f;   // w=1 sign: j bit2 = hh&1
    const bool h1b = (hh & 1) != 0;
    const bool h2b = (hh & 2) != 0;
    const f32x4 z = {0.f, 0.f, 0.f, 0.f};

    #pragma unroll 1
    for (int d = 0; d < 8; ++d) {
        float acc = 0.f;
        #pragma unroll
        for (int c = 0; c < 4; ++c) {
            const int cd = c * 8 + d;
            bf16x8 ar = wf[(cd * 64 + lane) * 2];
            bf16x8 ai = wf[(cd * 64 + lane) * 2 + 1];
            f32x4 yr = __builtin_amdgcn_mfma_f32_16x16x32_bf16(ar, bc[c], z, 0, 0, 0);
            f32x4 yi = __builtin_amdgcn_mfma_f32_16x16x32_bf16(ai, bc[c], z, 0, 0, 0);
            yr = __builtin_amdgcn_mfma_f32_16x16x32_bf16(ar, bm[c], yr, 0, 0, 0);
            yi = __builtin_amdgcn_mfma_f32_16x16x32_bf16(ai, bm[c], yi, 0, 0, 0);
            // q[reg] = |y_j|^2, j = hh*4 + reg (site = lane&15)
            float q0 = fmaf(yr[0], yr[0], yi[0] * yi[0]);
            float q1 = fmaf(yr[1], yr[1], yi[1] * yi[1]);
            float q2 = fmaf(yr[2], yr[2], yi[2] * yi[2]);
            float q3 = fmaf(yr[3], yr[3], yi[3] * yi[3]);
            // per-lane Walsh partials over its 4 j's
            float S  = (q0 + q1) + (q2 + q3);
            float A2 = (q0 + q1) - (q2 + q3);   // w=2: sign = reg bit1
            float A3 = (q0 - q1) + (q2 - q3);   // w=3: sign = reg bit0
            float p0 = sgn0 * S, p1 = sgn1 * S; // w=0 / w=1 (lane-uniform sign)
            float pS  = h1b ? p1 : p0;          // p(hh)   within S-family
            float pS_ = h1b ? p0 : p1;          // p(hh^1) within S-family
            float pA  = h1b ? A3 : A2;          // p(hh)   within A-family
            float pA_ = h1b ? A2 : A3;
            float pself = h2b ? pA  : pS;       // p(hh)
            float ps1   = h2b ? pA_ : pS_;      // p(hh^1)
            float ps2   = h2b ? pS  : pA;       // p(hh^2)
            float ps3   = h2b ? pS_ : pA_;      // p(hh^3)
            // combine the 4 hh lane-groups of this site: t_w for w = hh
            float S1a = pself + __shfl_xor(ps1, 16);
            float S1b = ps2 + __shfl_xor(ps3, 16);
            float t = S1a + __shfl_xor(S1b, 32);
            t = fminf(fmaxf(t, -1.f), 1.f);
            acc += acos_fast(t);
        }
        // out[b][d*4 + hh][ix][iy] - written exactly once
        out[((b * 32 + d * 4 + hh) * 32 + ix) * 32 + iy] = acc;
    }
}

extern "C" void kernel_launch(void* const* d_in, const int* in_sizes, int n_in,
                              void* d_out, int out_size, void* d_ws, size_t ws_size,
                              hipStream_t stream) {
    const float* x = (const float*)d_in[0];
    const float* params = (const float*)d_in[1];
    float* out = (float*)d_out;
    unsigned* wfrag = (unsigned*)d_ws;   // 32 cd * 64 lanes * 32 B = 64 KiB

    prep_kernel<<<32, 256, 0, stream>>>(params, wfrag);
    qconv_kernel<<<512, 256, 0, stream>>>(x, wfrag, out);
}